// Round 5
// baseline (3123.956 us; speedup 1.0000x reference)
//
#include <hip/hip_runtime.h>
#include <hip/hip_bf16.h>

#define HDIM 50
#define G3   150
#define TSEQ 512
#define BATCH 2048

// act[t][b][i] = t*(BATCH*HDIM) + b*HDIM + i   (209,715,200 B in d_ws)

// 13 named float4 weight regs per matrix (52 floats, last 2 zero-padded).
// "p##0 .x" (space!) — "p##0.x" would lex "0.x" as one pp-number.
#define W_DECL(p) float4 p##0,p##1,p##2,p##3,p##4,p##5,p##6,p##7,p##8,p##9,p##10,p##11,p##12
#define W_LOAD(p, base)  do { \
    const float* _w = (base); \
    p##0  = make_float4(_w[ 0],_w[ 1],_w[ 2],_w[ 3]); \
    p##1  = make_float4(_w[ 4],_w[ 5],_w[ 6],_w[ 7]); \
    p##2  = make_float4(_w[ 8],_w[ 9],_w[10],_w[11]); \
    p##3  = make_float4(_w[12],_w[13],_w[14],_w[15]); \
    p##4  = make_float4(_w[16],_w[17],_w[18],_w[19]); \
    p##5  = make_float4(_w[20],_w[21],_w[22],_w[23]); \
    p##6  = make_float4(_w[24],_w[25],_w[26],_w[27]); \
    p##7  = make_float4(_w[28],_w[29],_w[30],_w[31]); \
    p##8  = make_float4(_w[32],_w[33],_w[34],_w[35]); \
    p##9  = make_float4(_w[36],_w[37],_w[38],_w[39]); \
    p##10 = make_float4(_w[40],_w[41],_w[42],_w[43]); \
    p##11 = make_float4(_w[44],_w[45],_w[46],_w[47]); \
    p##12 = make_float4(_w[48],_w[49],0.f,0.f); \
} while(0)
// Pin one float4's components as opaque VGPR defs: the compiler cannot
// rematerialize the feeding loads inside the loop after this.
#define W_PIN1(q) asm volatile("" : "+v"(q.x), "+v"(q.y), "+v"(q.z), "+v"(q.w))
#define W_PIN(p) do { \
    W_PIN1(p##0); W_PIN1(p##1); W_PIN1(p##2);  W_PIN1(p##3);  W_PIN1(p##4); \
    W_PIN1(p##5); W_PIN1(p##6); W_PIN1(p##7);  W_PIN1(p##8);  W_PIN1(p##9); \
    W_PIN1(p##10); W_PIN1(p##11); W_PIN1(p##12); \
} while(0)
#define W_DOT4(acc, p, q, _t) \
    acc=fmaf(p##q .x,_t.x,acc); acc=fmaf(p##q .y,_t.y,acc); \
    acc=fmaf(p##q .z,_t.z,acc); acc=fmaf(p##q .w,_t.w,acc);
#define W_DOT(acc, p, v4) do { \
    float4 _t; \
    _t=(v4)[ 0]; W_DOT4(acc, p, 0, _t) \
    _t=(v4)[ 1]; W_DOT4(acc, p, 1, _t) \
    _t=(v4)[ 2]; W_DOT4(acc, p, 2, _t) \
    _t=(v4)[ 3]; W_DOT4(acc, p, 3, _t) \
    _t=(v4)[ 4]; W_DOT4(acc, p, 4, _t) \
    _t=(v4)[ 5]; W_DOT4(acc, p, 5, _t) \
    _t=(v4)[ 6]; W_DOT4(acc, p, 6, _t) \
    _t=(v4)[ 7]; W_DOT4(acc, p, 7, _t) \
    _t=(v4)[ 8]; W_DOT4(acc, p, 8, _t) \
    _t=(v4)[ 9]; W_DOT4(acc, p, 9, _t) \
    _t=(v4)[10]; W_DOT4(acc, p, 10, _t) \
    _t=(v4)[11]; W_DOT4(acc, p, 11, _t) \
    _t=(v4)[12]; acc=fmaf(p##12 .x,_t.x,acc); acc=fmaf(p##12 .y,_t.y,acc); \
} while(0)

template<int IN_DIM, int NB>
__global__ __launch_bounds__(192, 3)
void gru_layer_kernel(const float* __restrict__ xin_g,
                      float* __restrict__ act,
                      const float* __restrict__ Wih,
                      const float* __restrict__ Whh,
                      const float* __restrict__ bih,
                      const float* __restrict__ bhh)
{
    const int tid = threadIdx.x;
    const int b0  = blockIdx.x * NB;
    const int row = (tid < G3) ? tid : (G3 - 1);   // clamped: unconditional init

    __shared__ __align__(16) float h_s [NB][56];
    __shared__ __align__(16) float x_s [NB][56];
    __shared__ float s_rz[NB][100];
    __shared__ float s_xn[NB][50];
    __shared__ float s_hn[NB][50];
    __shared__ float x_row[(IN_DIM==1) ? NB : 1][(IN_DIM==1) ? TSEQ : 1];

    // ---- weights -> registers, then PIN so the t-loop can't reload them ----
    W_DECL(wh);
    W_LOAD(wh, Whh + row*HDIM);
    W_PIN(wh);
    float wi_scalar = 0.f;
    W_DECL(wi);
    if constexpr (IN_DIM == 1) {
        wi_scalar = Wih[row];
        asm volatile("" : "+v"(wi_scalar));
        wi0=wi1=wi2=wi3=wi4=wi5=wi6=wi7=wi8=wi9=wi10=wi11=wi12=make_float4(0.f,0.f,0.f,0.f);
    } else {
        W_LOAD(wi, Wih + row*IN_DIM);
        W_PIN(wi);
    }
    float b_i = bih[row];
    float b_h = bhh[row];
    asm volatile("" : "+v"(b_i), "+v"(b_h));

    for (int k = tid; k < NB*56; k += 192) h_s[k/56][k%56] = 0.f;
    for (int k = tid; k < NB*56; k += 192) x_s[k/56][k%56] = 0.f;

    if constexpr (IN_DIM == 1) {
        for (int k = tid; k < NB*TSEQ; k += 192)
            x_row[k/TSEQ][k%TSEQ] = xin_g[(size_t)(b0 + k/TSEQ)*TSEQ + (k%TSEQ)];
    }

    float xpre = 0.f;
    if (IN_DIM != 1 && tid < NB*HDIM) {
        xpre = xin_g[(size_t)(b0 + tid/HDIM)*HDIM + (tid%HDIM)];
    }
    __syncthreads();

    for (int t = 0; t < TSEQ; ++t) {
        // ---- stage 1: publish x(t); prefetch x(t+1) ----
        if constexpr (IN_DIM != 1) {
            if (tid < NB*HDIM) x_s[tid/HDIM][tid%HDIM] = xpre;
        }
        __syncthreads();
        if (IN_DIM != 1 && tid < NB*HDIM && t+1 < TSEQ) {
            xpre = xin_g[(size_t)(t+1)*(BATCH*HDIM) + (size_t)(b0 + tid/HDIM)*HDIM + (tid%HDIM)];
        }

        // ---- stage 2: gate GEMV, weights in pinned registers ----
        if (tid < G3) {
#pragma unroll
            for (int b = 0; b < NB; ++b) {
                float gx = b_i;
                if constexpr (IN_DIM == 1) {
                    gx = fmaf(wi_scalar, x_row[b][t], gx);
                } else {
                    const float4* x4 = (const float4*)&x_s[b][0];
                    W_DOT(gx, wi, x4);
                }
                float gh = b_h;
                const float4* h4 = (const float4*)&h_s[b][0];
                W_DOT(gh, wh, h4);

                if (tid < 100) {
                    s_rz[b][tid] = gx + gh;
                } else {
                    s_xn[b][tid-100] = gx;
                    s_hn[b][tid-100] = gh;
                }
            }
        }
        __syncthreads();

        // ---- stage 3: gate update ----
        if (tid < NB*HDIM) {
            const int b = tid / HDIM, u = tid % HDIM;
            float r = 1.f / (1.f + __expf(-s_rz[b][u]));
            float z = 1.f / (1.f + __expf(-s_rz[b][u+50]));
            float n = tanhf(s_xn[b][u] + r * s_hn[b][u]);
            float hn = (1.f - z)*n + z*h_s[b][u];
            h_s[b][u] = hn;
            act[(size_t)t*(BATCH*HDIM) + (size_t)(b0 + b)*HDIM + u] = hn;
        }
    }
}

__global__ __launch_bounds__(256)
void fc_sigmoid_kernel(const float* __restrict__ act,
                       const float* __restrict__ fcw,
                       const float* __restrict__ fcb,
                       float* __restrict__ out)
{
    int b = blockIdx.x*256 + threadIdx.x;
    if (b >= BATCH) return;
    const float* row = act + (size_t)(TSEQ-1)*(BATCH*HDIM) + (size_t)b*HDIM;
    float s = fcb[0];
#pragma unroll
    for (int j = 0; j < HDIM; ++j) s = fmaf(row[j], fcw[j], s);
    out[b] = 1.f / (1.f + __expf(-s));
}

extern "C" void kernel_launch(void* const* d_in, const int* in_sizes, int n_in,
                              void* d_out, int out_size, void* d_ws, size_t ws_size,
                              hipStream_t stream) {
    const float* x     = (const float*)d_in[0];
    const float* W_ih0 = (const float*)d_in[1];
    const float* W_hh0 = (const float*)d_in[2];
    const float* b_ih0 = (const float*)d_in[3];
    const float* b_hh0 = (const float*)d_in[4];
    const float* W_ih  = (const float*)d_in[5];
    const float* W_hh  = (const float*)d_in[6];
    const float* b_ih  = (const float*)d_in[7];
    const float* b_hh  = (const float*)d_in[8];
    const float* fc_w  = (const float*)d_in[9];
    const float* fc_b  = (const float*)d_in[10];
    float* out = (float*)d_out;

    float* act = (float*)d_ws;   // [512][2048][50] fp32

    constexpr int NB = 2;
    dim3 grid(BATCH / NB), block(192);

    gru_layer_kernel<1, NB><<<grid, block, 0, stream>>>(x, act, W_ih0, W_hh0, b_ih0, b_hh0);
    for (int l = 0; l < 3; ++l) {
        gru_layer_kernel<HDIM, NB><<<grid, block, 0, stream>>>(
            act, act,
            W_ih + (size_t)l*G3*HDIM, W_hh + (size_t)l*G3*HDIM,
            b_ih + (size_t)l*G3,      b_hh + (size_t)l*G3);
    }
    fc_sigmoid_kernel<<<BATCH/256, 256, 0, stream>>>(act, fc_w, fc_b, out);
}

// Round 6
// 3091.077 us; speedup vs baseline: 1.0106x; 1.0106x over previous
//
#include <hip/hip_runtime.h>
#include <hip/hip_bf16.h>

#define HDIM 50
#define G3   150
#define TSEQ 512
#define BATCH 2048

// act[t][b][i] = t*(BATCH*HDIM) + b*HDIM + i   (209,715,200 B in d_ws)

// 13 named float4 weight regs per matrix (52 floats, last 2 zero-padded).
// "p##0 .x" (space!) — "p##0.x" would lex "0.x" as one pp-number.
#define W_DECL(p) float4 p##0,p##1,p##2,p##3,p##4,p##5,p##6,p##7,p##8,p##9,p##10,p##11,p##12
#define W_LOAD(p, base)  do { \
    const float* _w = (base); \
    p##0  = make_float4(_w[ 0],_w[ 1],_w[ 2],_w[ 3]); \
    p##1  = make_float4(_w[ 4],_w[ 5],_w[ 6],_w[ 7]); \
    p##2  = make_float4(_w[ 8],_w[ 9],_w[10],_w[11]); \
    p##3  = make_float4(_w[12],_w[13],_w[14],_w[15]); \
    p##4  = make_float4(_w[16],_w[17],_w[18],_w[19]); \
    p##5  = make_float4(_w[20],_w[21],_w[22],_w[23]); \
    p##6  = make_float4(_w[24],_w[25],_w[26],_w[27]); \
    p##7  = make_float4(_w[28],_w[29],_w[30],_w[31]); \
    p##8  = make_float4(_w[32],_w[33],_w[34],_w[35]); \
    p##9  = make_float4(_w[36],_w[37],_w[38],_w[39]); \
    p##10 = make_float4(_w[40],_w[41],_w[42],_w[43]); \
    p##11 = make_float4(_w[44],_w[45],_w[46],_w[47]); \
    p##12 = make_float4(_w[48],_w[49],0.f,0.f); \
} while(0)
// Opaque VGPR defs: blocks rematerialization of the feeding loads.
#define W_PIN1(q) asm volatile("" : "+v"(q.x), "+v"(q.y), "+v"(q.z), "+v"(q.w))
#define W_PIN(p) do { \
    W_PIN1(p##0); W_PIN1(p##1); W_PIN1(p##2);  W_PIN1(p##3);  W_PIN1(p##4); \
    W_PIN1(p##5); W_PIN1(p##6); W_PIN1(p##7);  W_PIN1(p##8);  W_PIN1(p##9); \
    W_PIN1(p##10); W_PIN1(p##11); W_PIN1(p##12); \
} while(0)
#define W_DOT4(acc, p, q, _t) \
    acc=fmaf(p##q .x,_t.x,acc); acc=fmaf(p##q .y,_t.y,acc); \
    acc=fmaf(p##q .z,_t.z,acc); acc=fmaf(p##q .w,_t.w,acc);
#define W_DOT(acc, p, v4) do { \
    float4 _t; \
    _t=(v4)[ 0]; W_DOT4(acc, p, 0, _t) \
    _t=(v4)[ 1]; W_DOT4(acc, p, 1, _t) \
    _t=(v4)[ 2]; W_DOT4(acc, p, 2, _t) \
    _t=(v4)[ 3]; W_DOT4(acc, p, 3, _t) \
    _t=(v4)[ 4]; W_DOT4(acc, p, 4, _t) \
    _t=(v4)[ 5]; W_DOT4(acc, p, 5, _t) \
    _t=(v4)[ 6]; W_DOT4(acc, p, 6, _t) \
    _t=(v4)[ 7]; W_DOT4(acc, p, 7, _t) \
    _t=(v4)[ 8]; W_DOT4(acc, p, 8, _t) \
    _t=(v4)[ 9]; W_DOT4(acc, p, 9, _t) \
    _t=(v4)[10]; W_DOT4(acc, p, 10, _t) \
    _t=(v4)[11]; W_DOT4(acc, p, 11, _t) \
    _t=(v4)[12]; acc=fmaf(p##12 .x,_t.x,acc); acc=fmaf(p##12 .y,_t.y,acc); \
} while(0)

template<int IN_DIM, int NB>
__global__
__attribute__((amdgpu_flat_work_group_size(192, 192)))
__attribute__((amdgpu_waves_per_eu(3, 3)))   // pin allocator: 3 waves/EU -> ~170 VGPR budget, no spill-to-8-waves heuristic
void gru_layer_kernel(const float* __restrict__ xin_g,
                      float* __restrict__ act,
                      const float* __restrict__ Wih,
                      const float* __restrict__ Whh,
                      const float* __restrict__ bih,
                      const float* __restrict__ bhh)
{
    const int tid = threadIdx.x;
    const int b0  = blockIdx.x * NB;
    const int row = (tid < G3) ? tid : (G3 - 1);   // clamped: unconditional init

    __shared__ __align__(16) float h_s [NB][56];
    __shared__ __align__(16) float x_s [NB][56];
    __shared__ float s_rz[NB][100];
    __shared__ float s_xn[NB][50];
    __shared__ float s_hn[NB][50];
    __shared__ float x_row[(IN_DIM==1) ? NB : 1][(IN_DIM==1) ? TSEQ : 1];

    // ---- weights -> registers, then PIN so the t-loop can't reload them ----
    W_DECL(wh);
    W_LOAD(wh, Whh + row*HDIM);
    W_PIN(wh);
    float wi_scalar = 0.f;
    W_DECL(wi);
    if constexpr (IN_DIM == 1) {
        wi_scalar = Wih[row];
        asm volatile("" : "+v"(wi_scalar));
        wi0=wi1=wi2=wi3=wi4=wi5=wi6=wi7=wi8=wi9=wi10=wi11=wi12=make_float4(0.f,0.f,0.f,0.f);
    } else {
        W_LOAD(wi, Wih + row*IN_DIM);
        W_PIN(wi);
    }
    float b_i = bih[row];
    float b_h = bhh[row];
    asm volatile("" : "+v"(b_i), "+v"(b_h));

    for (int k = tid; k < NB*56; k += 192) h_s[k/56][k%56] = 0.f;
    for (int k = tid; k < NB*56; k += 192) x_s[k/56][k%56] = 0.f;

    if constexpr (IN_DIM == 1) {
        for (int k = tid; k < NB*TSEQ; k += 192)
            x_row[k/TSEQ][k%TSEQ] = xin_g[(size_t)(b0 + k/TSEQ)*TSEQ + (k%TSEQ)];
    }

    float xpre = 0.f;
    if (IN_DIM != 1 && tid < NB*HDIM) {
        xpre = xin_g[(size_t)(b0 + tid/HDIM)*HDIM + (tid%HDIM)];
    }
    __syncthreads();

    for (int t = 0; t < TSEQ; ++t) {
        // ---- stage 1: publish x(t); prefetch x(t+1) ----
        if constexpr (IN_DIM != 1) {
            if (tid < NB*HDIM) x_s[tid/HDIM][tid%HDIM] = xpre;
        }
        __syncthreads();
        if (IN_DIM != 1 && tid < NB*HDIM && t+1 < TSEQ) {
            xpre = xin_g[(size_t)(t+1)*(BATCH*HDIM) + (size_t)(b0 + tid/HDIM)*HDIM + (tid%HDIM)];
        }

        // ---- stage 2: gate GEMV, weights in pinned registers ----
        if (tid < G3) {
#pragma unroll
            for (int b = 0; b < NB; ++b) {
                float gx = b_i;
                if constexpr (IN_DIM == 1) {
                    gx = fmaf(wi_scalar, x_row[b][t], gx);
                } else {
                    const float4* x4 = (const float4*)&x_s[b][0];
                    W_DOT(gx, wi, x4);
                }
                float gh = b_h;
                const float4* h4 = (const float4*)&h_s[b][0];
                W_DOT(gh, wh, h4);

                if (tid < 100) {
                    s_rz[b][tid] = gx + gh;
                } else {
                    s_xn[b][tid-100] = gx;
                    s_hn[b][tid-100] = gh;
                }
            }
        }
        __syncthreads();

        // ---- stage 3: gate update ----
        if (tid < NB*HDIM) {
            const int b = tid / HDIM, u = tid % HDIM;
            float r = 1.f / (1.f + __expf(-s_rz[b][u]));
            float z = 1.f / (1.f + __expf(-s_rz[b][u+50]));
            float n = tanhf(s_xn[b][u] + r * s_hn[b][u]);
            float hn = (1.f - z)*n + z*h_s[b][u];
            h_s[b][u] = hn;
            act[(size_t)t*(BATCH*HDIM) + (size_t)(b0 + b)*HDIM + u] = hn;
        }
    }
}

__global__ __launch_bounds__(256)
void fc_sigmoid_kernel(const float* __restrict__ act,
                       const float* __restrict__ fcw,
                       const float* __restrict__ fcb,
                       float* __restrict__ out)
{
    int b = blockIdx.x*256 + threadIdx.x;
    if (b >= BATCH) return;
    const float* row = act + (size_t)(TSEQ-1)*(BATCH*HDIM) + (size_t)b*HDIM;
    float s = fcb[0];
#pragma unroll
    for (int j = 0; j < HDIM; ++j) s = fmaf(row[j], fcw[j], s);
    out[b] = 1.f / (1.f + __expf(-s));
}

extern "C" void kernel_launch(void* const* d_in, const int* in_sizes, int n_in,
                              void* d_out, int out_size, void* d_ws, size_t ws_size,
                              hipStream_t stream) {
    const float* x     = (const float*)d_in[0];
    const float* W_ih0 = (const float*)d_in[1];
    const float* W_hh0 = (const float*)d_in[2];
    const float* b_ih0 = (const float*)d_in[3];
    const float* b_hh0 = (const float*)d_in[4];
    const float* W_ih  = (const float*)d_in[5];
    const float* W_hh  = (const float*)d_in[6];
    const float* b_ih  = (const float*)d_in[7];
    const float* b_hh  = (const float*)d_in[8];
    const float* fc_w  = (const float*)d_in[9];
    const float* fc_b  = (const float*)d_in[10];
    float* out = (float*)d_out;

    float* act = (float*)d_ws;   // [512][2048][50] fp32

    constexpr int NB = 2;
    dim3 grid(BATCH / NB), block(192);

    gru_layer_kernel<1, NB><<<grid, block, 0, stream>>>(x, act, W_ih0, W_hh0, b_ih0, b_hh0);
    for (int l = 0; l < 3; ++l) {
        gru_layer_kernel<HDIM, NB><<<grid, block, 0, stream>>>(
            act, act,
            W_ih + (size_t)l*G3*HDIM, W_hh + (size_t)l*G3*HDIM,
            b_ih + (size_t)l*G3,      b_hh + (size_t)l*G3);
    }
    fc_sigmoid_kernel<<<BATCH/256, 256, 0, stream>>>(act, fc_w, fc_b, out);
}